// Round 1
// baseline (318.002 us; speedup 1.0000x reference)
//
#include <hip/hip_runtime.h>
#include <cstdint>

typedef unsigned short u16;
typedef short s8v __attribute__((ext_vector_type(8)));
typedef float f4v __attribute__((ext_vector_type(4)));

// fp32 -> bf16 round-to-nearest-even (bit trick)
__device__ __forceinline__ u16 f2b(float f) {
  uint32_t u = __float_as_uint(f);
  u = (u + 0x7FFFu + ((u >> 16) & 1u)) >> 16;
  return (u16)u;
}

// ---------------------------------------------------------------------------
// Convert kernels
// ---------------------------------------------------------------------------

// x fp32 -> bf16, 4 elems/thread
__global__ void conv_x(const float* __restrict__ x, u16* __restrict__ xb) {
  int i = blockIdx.x * blockDim.x + threadIdx.x;
  float4 v = ((const float4*)x)[i];
  uint2 o;
  o.x = (uint32_t)f2b(v.x) | ((uint32_t)f2b(v.y) << 16);
  o.y = (uint32_t)f2b(v.z) | ((uint32_t)f2b(v.w) << 16);
  ((uint2*)xb)[i] = o;
}

// W [16][1024][64] fp32 -> dst[(h*64+d)][m] bf16 (B^T layout), 64x64 LDS transpose
__global__ void convT_w(const float* __restrict__ W, u16* __restrict__ dst) {
  __shared__ u16 tile[64][65];
  const int m0 = blockIdx.x * 64;
  const int h  = blockIdx.y;
  const int c  = threadIdx.x & 63;
  const int r4 = threadIdx.x >> 6;
  const float* Wh = W + (size_t)h * 65536;
  for (int i = 0; i < 16; ++i) {
    int lm = i * 4 + r4;
    tile[lm][c] = f2b(Wh[(size_t)(m0 + lm) * 64 + c]);   // coalesced read over d
  }
  __syncthreads();
  for (int i = 0; i < 16; ++i) {
    int dd = i * 4 + r4;
    dst[((size_t)h * 64 + dd) * 1024 + m0 + c] = tile[c][dd];  // coalesced write over m
  }
}

// W_O flat [1024 k][1024 m] fp32 -> dst[m][k] bf16 (B^T layout)
__global__ void convT_wo(const float* __restrict__ W, u16* __restrict__ dst) {
  __shared__ u16 tile[64][65];
  const int k0 = blockIdx.x * 64;
  const int m0 = blockIdx.y * 64;
  const int c  = threadIdx.x & 63;
  const int r4 = threadIdx.x >> 6;
  for (int i = 0; i < 16; ++i) {
    int lk = i * 4 + r4;
    tile[lk][c] = f2b(W[(size_t)(k0 + lk) * 1024 + m0 + c]);
  }
  __syncthreads();
  for (int i = 0; i < 16; ++i) {
    int lm = i * 4 + r4;
    dst[(size_t)(m0 + lm) * 1024 + k0 + c] = tile[c][lm];
  }
}

// bqkv[3072] = concat(b_Q, b_K, b_V) flat; bsum[1024] = sum_h b_O[h][m]
__global__ void conv_bias(const float* __restrict__ bQ, const float* __restrict__ bK,
                          const float* __restrict__ bV, const float* __restrict__ bO,
                          float* __restrict__ bqkv, float* __restrict__ bsum) {
  int t = blockIdx.x * 256 + threadIdx.x;
  if (t < 1024)       bqkv[t] = bQ[t];
  else if (t < 2048)  bqkv[t] = bK[t - 1024];
  else if (t < 3072)  bqkv[t] = bV[t - 2048];
  else {
    int m = t - 3072;
    float s = 0.f;
    for (int hh = 0; hh < 16; ++hh) s += bO[hh * 1024 + m];
    bsum[m] = s;
  }
}

// ---------------------------------------------------------------------------
// bf16 MFMA GEMM: C[M][N] = A[M][K] * BT[N][K]^T + bias[col]
// 128x128 block tile, BK=32, 256 threads = 4 waves (2x2), each wave 64x64 (4x4
// mfma_f32_16x16x32_bf16 tiles). LDS rows padded to 40 bf16 (2-way max conflict).
// ---------------------------------------------------------------------------
template<bool OUT_F32>
__global__ void gemm_bt(const u16* __restrict__ A, const u16* __restrict__ BT,
                        const float* __restrict__ bias, void* __restrict__ Cout,
                        int N, int K) {
  __shared__ __align__(16) u16 sA[128 * 40];
  __shared__ __align__(16) u16 sB[128 * 40];
  const int tid  = threadIdx.x;
  const int lane = tid & 63, wave = tid >> 6;
  const int wm = wave >> 1, wn = wave & 1;
  const int lq = lane & 15, quad = lane >> 4;
  const int m0 = blockIdx.y * 128, n0 = blockIdx.x * 128;

  f4v acc[4][4] = {};

  for (int k0 = 0; k0 < K; k0 += 32) {
    __syncthreads();
    // stage A-tile 128x32 and B-tile 128x32 (bf16): 512 16B segs each, 2/thread
    for (int i = 0; i < 2; ++i) {
      int s = tid + i * 256;
      int row = s >> 2, part = s & 3;
      *(uint4*)&sA[row * 40 + part * 8] =
          *(const uint4*)(A + (size_t)(m0 + row) * K + k0 + part * 8);
      *(uint4*)&sB[row * 40 + part * 8] =
          *(const uint4*)(BT + (size_t)(n0 + row) * K + k0 + part * 8);
    }
    __syncthreads();
    s8v af[4], bfr[4];
    for (int i = 0; i < 4; ++i)
      af[i]  = *(const s8v*)&sA[(wm * 64 + i * 16 + lq) * 40 + quad * 8];
    for (int j = 0; j < 4; ++j)
      bfr[j] = *(const s8v*)&sB[(wn * 64 + j * 16 + lq) * 40 + quad * 8];
    for (int i = 0; i < 4; ++i)
      for (int j = 0; j < 4; ++j)
        acc[i][j] = __builtin_amdgcn_mfma_f32_16x16x32_bf16(af[i], bfr[j], acc[i][j], 0, 0, 0);
  }

  // epilogue: C/D layout row = quad*4+r, col = lane&15
  for (int i = 0; i < 4; ++i)
    for (int j = 0; j < 4; ++j) {
      int row = m0 + wm * 64 + i * 16 + quad * 4;
      int col = n0 + wn * 64 + j * 16 + lq;
      float bb = bias[col];
      for (int r = 0; r < 4; ++r) {
        float v = acc[i][j][r] + bb;
        if (OUT_F32) ((float*)Cout)[(size_t)(row + r) * N + col] = v;
        else         ((u16*)Cout)[(size_t)(row + r) * N + col] = f2b(v);
      }
    }
}

// ---------------------------------------------------------------------------
// Flash attention (causal, online softmax). 1 wave / 16-query tile.
// QKV packed bf16 [4096][3072]: cols 0-1023 Q, 1024-2047 K, 2048-3071 V (h*64+d).
// Z out bf16 [4096][1024].
// ---------------------------------------------------------------------------
__global__ __launch_bounds__(64) void attn_fwd(const u16* __restrict__ QKV,
                                               u16* __restrict__ Z) {
  __shared__ __align__(16) u16 sP[16 * 40];
  const int lane = threadIdx.x;
  const int lq = lane & 15, quad = lane >> 4;
  const int b = blockIdx.z, h = blockIdx.y;
  const int qt = (int)gridDim.x - 1 - (int)blockIdx.x;  // heavy tiles dispatch first
  const int q0 = qt * 16;
  const int RS = 3072;
  const u16* base = QKV + (size_t)b * 2048 * RS;
  const u16* Qb = base + h * 64;
  const u16* Kb = base + 1024 + h * 64;
  const u16* Vb = base + 2048 + h * 64;

  // Q A-frags: lane holds Q[q0+lq][d = 32*half + quad*8 + j]
  s8v qf0 = *(const s8v*)&Qb[(size_t)(q0 + lq) * RS + quad * 8];
  s8v qf1 = *(const s8v*)&Qb[(size_t)(q0 + lq) * RS + 32 + quad * 8];

  f4v zacc[4] = {};                      // dc (d-chunk of 16) x reg(r)
  float mrow[4], lsum[4];
  for (int r = 0; r < 4; ++r) { mrow[r] = -3.0e38f; lsum[r] = 0.f; }

  const int nchunk = (q0 + 15) / 32 + 1;
  for (int c = 0; c < nchunk; ++c) {
    const int k0 = c * 32;
    f4v sacc0 = {}, sacc1 = {};
    {
      const u16* kr0 = &Kb[(size_t)(k0 + lq) * RS + quad * 8];
      const u16* kr1 = &Kb[(size_t)(k0 + 16 + lq) * RS + quad * 8];
      s8v kf;
      kf = *(const s8v*)kr0;        sacc0 = __builtin_amdgcn_mfma_f32_16x16x32_bf16(qf0, kf, sacc0, 0, 0, 0);
      kf = *(const s8v*)(kr0 + 32); sacc0 = __builtin_amdgcn_mfma_f32_16x16x32_bf16(qf1, kf, sacc0, 0, 0, 0);
      kf = *(const s8v*)kr1;        sacc1 = __builtin_amdgcn_mfma_f32_16x16x32_bf16(qf0, kf, sacc1, 0, 0, 0);
      kf = *(const s8v*)(kr1 + 32); sacc1 = __builtin_amdgcn_mfma_f32_16x16x32_bf16(qf1, kf, sacc1, 0, 0, 0);
    }
    // scores in C layout: row q = q0+quad*4+r, col key = k0(+16)+lq
    float s0[4], s1[4], t[4];
    const int qrow = q0 + quad * 4;
    for (int r = 0; r < 4; ++r) {
      s0[r] = sacc0[r] * 0.125f;
      s1[r] = sacc1[r] * 0.125f;
      if (k0 + lq > qrow + r)      s0[r] = -3.0e38f;
      if (k0 + 16 + lq > qrow + r) s1[r] = -3.0e38f;
      t[r] = fmaxf(s0[r], s1[r]);
    }
    for (int off = 1; off < 16; off <<= 1)
      for (int r = 0; r < 4; ++r) t[r] = fmaxf(t[r], __shfl_xor(t[r], off, 64));

    float alpha[4], p0[4], p1[4], u[4];
    for (int r = 0; r < 4; ++r) {
      float mnew = fmaxf(mrow[r], t[r]);
      alpha[r] = __expf(mrow[r] - mnew);
      p0[r] = __expf(s0[r] - mnew);
      p1[r] = __expf(s1[r] - mnew);
      u[r] = p0[r] + p1[r];
      mrow[r] = mnew;
    }
    for (int off = 1; off < 16; off <<= 1)
      for (int r = 0; r < 4; ++r) u[r] += __shfl_xor(u[r], off, 64);
    for (int r = 0; r < 4; ++r) lsum[r] = lsum[r] * alpha[r] + u[r];
    for (int dc = 0; dc < 4; ++dc)
      for (int r = 0; r < 4; ++r) zacc[dc][r] *= alpha[r];

    // P: C layout -> LDS (rows 16 x 32 keys, stride 40)
    for (int r = 0; r < 4; ++r) {
      sP[(quad * 4 + r) * 40 + lq]      = f2b(p0[r]);
      sP[(quad * 4 + r) * 40 + 16 + lq] = f2b(p1[r]);
    }
    __syncthreads();
    // P A-frag: lane holds P[q=lq][k=quad*8+j]
    s8v pf = *(const s8v*)&sP[lq * 40 + quad * 8];
    // V B-frags: lane holds V[k=quad*8+j][d=dc*16+lq]
    const u16* vb0 = &Vb[(size_t)(k0 + quad * 8) * RS];
    for (int dc = 0; dc < 4; ++dc) {
      s8v vf;
      for (int j = 0; j < 8; ++j) vf[j] = (short)vb0[(size_t)j * RS + dc * 16 + lq];
      zacc[dc] = __builtin_amdgcn_mfma_f32_16x16x32_bf16(pf, vf, zacc[dc], 0, 0, 0);
    }
    __syncthreads();
  }

  float inv[4];
  for (int r = 0; r < 4; ++r) inv[r] = 1.0f / lsum[r];
  for (int dc = 0; dc < 4; ++dc)
    for (int r = 0; r < 4; ++r) {
      size_t row = (size_t)b * 2048 + q0 + quad * 4 + r;
      Z[row * 1024 + h * 64 + dc * 16 + lq] = f2b(zacc[dc][r] * inv[r]);
    }
}

// ---------------------------------------------------------------------------
// Launch
// ---------------------------------------------------------------------------
extern "C" void kernel_launch(void* const* d_in, const int* in_sizes, int n_in,
                              void* d_out, int out_size, void* d_ws, size_t ws_size,
                              hipStream_t stream) {
  const float* x  = (const float*)d_in[0];
  const float* WQ = (const float*)d_in[1];
  const float* bQ = (const float*)d_in[2];
  const float* WK = (const float*)d_in[3];
  const float* bK = (const float*)d_in[4];
  const float* WV = (const float*)d_in[5];
  const float* WO = (const float*)d_in[6];
  const float* bV = (const float*)d_in[7];
  const float* bO = (const float*)d_in[8];
  float* out = (float*)d_out;

  uint8_t* ws = (uint8_t*)d_ws;
  u16*   xb    = (u16*)(ws);                       //  8 MB  [4096][1024]
  u16*   WTqkv = (u16*)(ws + 8388608);             //  6 MB  [3072][1024]
  u16*   WOT   = (u16*)(ws + 14680064);            //  2 MB  [1024][1024]
  u16*   QKV   = (u16*)(ws + 16777216);            // 24 MB  [4096][3072]
  u16*   Zb    = (u16*)(ws + 41943040);            //  8 MB  [4096][1024]
  float* bqkv  = (float*)(ws + 50331648);          // 12 KB
  float* bsum  = (float*)(ws + 50343936);          //  4 KB

  conv_x<<<4096, 256, 0, stream>>>(x, xb);
  convT_w<<<dim3(16, 16), 256, 0, stream>>>(WQ, WTqkv);
  convT_w<<<dim3(16, 16), 256, 0, stream>>>(WK, WTqkv + 1024 * 1024);
  convT_w<<<dim3(16, 16), 256, 0, stream>>>(WV, WTqkv + 2048 * 1024);
  convT_wo<<<dim3(16, 16), 256, 0, stream>>>(WO, WOT);
  conv_bias<<<16, 256, 0, stream>>>(bQ, bK, bV, bO, bqkv, bsum);

  // QKV projection: [4096x1024] x [1024x3072] -> bf16 QKV
  gemm_bt<false><<<dim3(24, 32), 256, 0, stream>>>(xb, WTqkv, bqkv, (void*)QKV, 3072, 1024);
  // attention
  attn_fwd<<<dim3(128, 16, 2), 64, 0, stream>>>(QKV, Zb);
  // output projection: [4096x1024] x [1024x1024] -> fp32 out (+ sum_h b_O)
  gemm_bt<true><<<dim3(8, 32), 256, 0, stream>>>(Zb, WOT, bsum, (void*)out, 1024, 1024);
}